// Round 1
// baseline (820.138 us; speedup 1.0000x reference)
//
#include <hip/hip_runtime.h>
#include <math.h>

#define HD 1024
#define MD 4096
#define WD 4096
#define RD 4
#define NWD 2
#define MODESD 5
#define EPSF 0.001f

// ---- d_out offsets (floats), in reference return order ----
#define O_WORDS 0            // read_words   R*WD        = 16384
#define O_NM    16384        // new_memory   MD*WD       = 16777216
#define O_RW    16793600     // read_weights R*MD        = 16384
#define O_WW    16809984     // write_weights NW*MD      = 8192
#define O_LINK  16818176     // link         NW*MD*MD    = 33554432
#define O_PREC  50372608     // precedence   NW*MD       = 8192
#define O_USAGE 50380800     // usage        MD          = 4096

// ---- workspace offsets (floats) ----
#define WS_WV   0            // 8192
#define WS_EV   8192         // 8192 (sigmoid)
#define WS_WK   16384        // 8192 (sigmoid)
#define WS_RK   24576        // 16384
#define WS_FG   40960        // 4  (sigmoid)
#define WS_AG   40976        // 2  (sigmoid)
#define WS_WG   40992        // 2  (sigmoid)
#define WS_RM   41008        // 20 (sigmoid)
#define WS_WSTR 41040        // 2
#define WS_RS   41056        // 4
#define WS_KN   41072        // 2
#define WS_RKN  41088        // 4
#define WS_UPRE 41104        // 4096
#define WS_SIM  45200        // NW*MD = 8192
#define WS_RDOT 53392        // R*MD  = 16384
#define WS_NMN  69776        // 4096
#define WS_CONT 73872        // R*MD  = 16384
#define WS_FWD  90256        // R*NW*MD = 32768
#define WS_BWD  123024       // R*NW*MD = 32768   (zeroed each launch)

__device__ __forceinline__ float waveReduceSum(float v) {
#pragma unroll
  for (int o = 32; o; o >>= 1) v += __shfl_down(v, o, 64);
  return v;
}

// ---------------- GEMV: out[row] = act(x . W[row,:] + b[row]) ----------------
// block = 256 (4 waves), one row per wave
__global__ void gemv_kernel(const float* __restrict__ W, const float* __restrict__ b,
                            const float* __restrict__ x, float* __restrict__ out,
                            int rows, int act) {
  __shared__ float4 xs[HD / 4];
  int t = threadIdx.x;
  const float4* x4 = (const float4*)x;
  xs[t] = x4[t];
  __syncthreads();
  int wave = t >> 6, lane = t & 63;
  int row = blockIdx.x * 4 + wave;
  if (row >= rows) return;
  const float4* W4 = (const float4*)(W + (size_t)row * HD);
  float acc = 0.f;
#pragma unroll
  for (int i = 0; i < 4; ++i) {
    float4 w = W4[i * 64 + lane];
    float4 xv = xs[i * 64 + lane];
    acc += w.x * xv.x + w.y * xv.y + w.z * xv.z + w.w * xv.w;
  }
  acc = waveReduceSum(acc);
  if (lane == 0) {
    float v = acc + b[row];
    if (act) v = 1.f / (1.f + expf(-v));
    out[row] = v;
  }
}

// ---------------- key norms: ||wk[w]||, ||rk[r]|| ----------------
__global__ void norms_kernel(const float* __restrict__ wk, const float* __restrict__ rk,
                             float* __restrict__ kn, float* __restrict__ rkn) {
  int v = blockIdx.x;  // 0..5
  const float* p = (v < 2) ? (wk + v * WD) : (rk + (v - 2) * WD);
  float s = 0.f;
  for (int d = threadIdx.x; d < WD; d += 256) { float t = p[d]; s += t * t; }
  s = waveReduceSum(s);
  __shared__ float sh[4];
  int wave = threadIdx.x >> 6, lane = threadIdx.x & 63;
  if (lane == 0) sh[wave] = s;
  __syncthreads();
  if (threadIdx.x == 0) {
    float r = sqrtf(sh[0] + sh[1] + sh[2] + sh[3]);
    if (v < 2) kn[v] = r; else rkn[v - 2] = r;
  }
}

// ---------------- usage pre-allocation ----------------
__global__ void usage_kernel(const float* __restrict__ pusage, const float* __restrict__ pww,
                             const float* __restrict__ prw, const float* __restrict__ fg,
                             float* __restrict__ upre) {
  int m = blockIdx.x * 256 + threadIdx.x;
  float pw = 1.f;
#pragma unroll
  for (int w = 0; w < NWD; ++w) pw *= pww[w * MD + m];
  float pu = pusage[m];
  float u = pu + (1.f - pu) * (1.f - pw);
  float pr = 1.f;
#pragma unroll
  for (int r = 0; r < RD; ++r) pr *= fg[r] * prw[r * MD + m];
  upre[m] = u * (1.f - pr);
}

// ---------------- write-key similarity over memory ----------------
__global__ void sim_kernel(const float* __restrict__ mem, const float* __restrict__ wk,
                           const float* __restrict__ kn, float* __restrict__ sim) {
  int m = blockIdx.x;
  int t = threadIdx.x;
  const float4* row = (const float4*)(mem + (size_t)m * WD);
  const float4* k0 = (const float4*)wk;
  const float4* k1 = (const float4*)(wk + WD);
  float d0 = 0, d1 = 0, s = 0;
  for (int i = t; i < WD / 4; i += 256) {
    float4 v = row[i], a = k0[i], b = k1[i];
    d0 += v.x * a.x + v.y * a.y + v.z * a.z + v.w * a.w;
    d1 += v.x * b.x + v.y * b.y + v.z * b.z + v.w * b.w;
    s  += v.x * v.x + v.y * v.y + v.z * v.z + v.w * v.w;
  }
  d0 = waveReduceSum(d0); d1 = waveReduceSum(d1); s = waveReduceSum(s);
  __shared__ float sh[3][4];
  int wave = t >> 6, lane = t & 63;
  if (lane == 0) { sh[0][wave] = d0; sh[1][wave] = d1; sh[2][wave] = s; }
  __syncthreads();
  if (t == 0) {
    float D0 = sh[0][0] + sh[0][1] + sh[0][2] + sh[0][3];
    float D1 = sh[1][0] + sh[1][1] + sh[1][2] + sh[1][3];
    float S  = sh[2][0] + sh[2][1] + sh[2][2] + sh[2][3];
    float mn = sqrtf(S);
    sim[0 * MD + m] = D0 / (kn[0] * mn + EPSF);
    sim[1 * MD + m] = D1 / (kn[1] * mn + EPSF);
  }
}

// ---------------- sequential write-weights / allocation / precedence ----------------
// single block, 1024 threads; LDS: 16+16+8+16+4 = 60 KB
__global__ __launch_bounds__(1024) void ww_kernel(
    const float* __restrict__ sim, const float* __restrict__ upre,
    const float* __restrict__ wstr, const float* __restrict__ ag,
    const float* __restrict__ wg, const float* __restrict__ pprec,
    float* __restrict__ out_ww, float* __restrict__ out_prec,
    float* __restrict__ out_usage) {
  __shared__ float u_s[MD];
  __shared__ float sv[MD];
  __shared__ unsigned short si[MD];
  __shared__ float a_s[MD];
  __shared__ float red[1024];
  int t = threadIdx.x;
  for (int m = t; m < MD; m += 1024) u_s[m] = upre[m];
  __syncthreads();

  for (int head = 0; head < NWD; ++head) {
    float beta = 1.f + log1pf(expf(wstr[head]));
    float agv = ag[head], wgv = wg[head];

    // softmax stats of sim[head]*beta (content weights computed on the fly later)
    float mx = -3.4e38f;
    for (int m = t; m < MD; m += 1024) mx = fmaxf(mx, sim[head * MD + m] * beta);
    red[t] = mx; __syncthreads();
    for (int s = 512; s; s >>= 1) { if (t < s) red[t] = fmaxf(red[t], red[t + s]); __syncthreads(); }
    mx = red[0]; __syncthreads();
    float sm = 0.f;
    for (int m = t; m < MD; m += 1024) sm += expf(sim[head * MD + m] * beta - mx);
    red[t] = sm; __syncthreads();
    for (int s = 512; s; s >>= 1) { if (t < s) red[t] += red[t + s]; __syncthreads(); }
    float inv = 1.f / red[0]; __syncthreads();

    // allocation: stable ascending sort of u = EPS + (1-EPS)*usage
    for (int m = t; m < MD; m += 1024) { sv[m] = EPSF + (1.f - EPSF) * u_s[m]; si[m] = (unsigned short)m; }
    __syncthreads();
    for (int k = 2; k <= MD; k <<= 1) {
      for (int j = k >> 1; j > 0; j >>= 1) {
        for (int i = t; i < MD; i += 1024) {
          int ixj = i ^ j;
          if (ixj > i) {
            float v1 = sv[i], v2 = sv[ixj];
            unsigned short i1 = si[i], i2 = si[ixj];
            bool gt = (v1 > v2) || (v1 == v2 && i1 > i2);
            bool up = ((i & k) == 0);
            if (gt == up) { sv[i] = v2; sv[ixj] = v1; si[i] = i2; si[ixj] = i1; }
          }
        }
        __syncthreads();
      }
    }
    // exclusive cumprod over sorted values (chunk of 4 per thread + multiplicative scan)
    float l0 = sv[t * 4 + 0], l1 = sv[t * 4 + 1], l2 = sv[t * 4 + 2], l3 = sv[t * 4 + 3];
    unsigned short s0 = si[t * 4 + 0], s1 = si[t * 4 + 1], s2 = si[t * 4 + 2], s3 = si[t * 4 + 3];
    red[t] = l0 * l1 * l2 * l3; __syncthreads();
    for (int off = 1; off < 1024; off <<= 1) {
      float val = (t >= off) ? red[t - off] : 1.f;
      __syncthreads();
      red[t] *= val;
      __syncthreads();
    }
    float carry = (t > 0) ? red[t - 1] : 1.f;
    __syncthreads();
    float e0 = carry, e1 = e0 * l0, e2 = e1 * l1, e3 = e2 * l2;
    a_s[s0] = (1.f - l0) * e0;
    a_s[s1] = (1.f - l1) * e1;
    a_s[s2] = (1.f - l2) * e2;
    a_s[s3] = (1.f - l3) * e3;
    __syncthreads();

    // usage update + write weights
    float agwg = agv * wgv;
    for (int m = t; m < MD; m += 1024) {
      float cwv = expf(sim[head * MD + m] * beta - mx) * inv;
      float a = a_s[m];
      float uu = u_s[m];
      u_s[m] = uu + (1.f - uu) * agwg * a;
      out_ww[head * MD + m] = wgv * (agv * a + (1.f - agv) * cwv);
    }
    __syncthreads();
  }

  // precedence + usage out
  for (int head = 0; head < NWD; ++head) {
    float s = 0.f;
    for (int m = t; m < MD; m += 1024) s += out_ww[head * MD + m];
    red[t] = s; __syncthreads();
    for (int ss = 512; ss; ss >>= 1) { if (t < ss) red[t] += red[t + ss]; __syncthreads(); }
    float wsum = red[0]; __syncthreads();
    for (int m = t; m < MD; m += 1024)
      out_prec[head * MD + m] = (1.f - wsum) * pprec[head * MD + m] + out_ww[head * MD + m];
  }
  for (int m = t; m < MD; m += 1024) out_usage[m] = u_s[m];
}

// ---------------- new_memory + fused rdot + new norms ----------------
__global__ void newmem_kernel(const float* __restrict__ mem, const float* __restrict__ ww,
                              const float* __restrict__ ev, const float* __restrict__ wvv,
                              const float* __restrict__ rk, float* __restrict__ nm_out,
                              float* __restrict__ rdot, float* __restrict__ nmn) {
  int m = blockIdx.x;
  int t = threadIdx.x;
  float w0 = ww[m], w1 = ww[MD + m];
  const float4* row = (const float4*)(mem + (size_t)m * WD);
  const float4* e0 = (const float4*)ev;
  const float4* e1 = (const float4*)(ev + WD);
  const float4* v0 = (const float4*)wvv;
  const float4* v1 = (const float4*)(wvv + WD);
  const float4* k0 = (const float4*)rk;
  const float4* k1 = (const float4*)(rk + WD);
  const float4* k2 = (const float4*)(rk + 2 * WD);
  const float4* k3 = (const float4*)(rk + 3 * WD);
  float4* outp = (float4*)(nm_out + (size_t)m * WD);
  float r0 = 0, r1 = 0, r2 = 0, r3 = 0, s2 = 0;
  for (int i = t; i < WD / 4; i += 256) {
    float4 mv = row[i], ea = e0[i], eb = e1[i], va = v0[i], vb = v1[i];
    float4 o;
    o.x = mv.x * (1.f - w0 * ea.x) * (1.f - w1 * eb.x) + w0 * va.x + w1 * vb.x;
    o.y = mv.y * (1.f - w0 * ea.y) * (1.f - w1 * eb.y) + w0 * va.y + w1 * vb.y;
    o.z = mv.z * (1.f - w0 * ea.z) * (1.f - w1 * eb.z) + w0 * va.z + w1 * vb.z;
    o.w = mv.w * (1.f - w0 * ea.w) * (1.f - w1 * eb.w) + w0 * va.w + w1 * vb.w;
    outp[i] = o;
    float4 a = k0[i]; r0 += o.x * a.x + o.y * a.y + o.z * a.z + o.w * a.w;
    float4 b = k1[i]; r1 += o.x * b.x + o.y * b.y + o.z * b.z + o.w * b.w;
    float4 c = k2[i]; r2 += o.x * c.x + o.y * c.y + o.z * c.z + o.w * c.w;
    float4 d = k3[i]; r3 += o.x * d.x + o.y * d.y + o.z * d.z + o.w * d.w;
    s2 += o.x * o.x + o.y * o.y + o.z * o.z + o.w * o.w;
  }
  r0 = waveReduceSum(r0); r1 = waveReduceSum(r1); r2 = waveReduceSum(r2);
  r3 = waveReduceSum(r3); s2 = waveReduceSum(s2);
  __shared__ float sh[5][4];
  int wave = t >> 6, lane = t & 63;
  if (lane == 0) { sh[0][wave] = r0; sh[1][wave] = r1; sh[2][wave] = r2; sh[3][wave] = r3; sh[4][wave] = s2; }
  __syncthreads();
  if (t == 0) {
    float R0 = sh[0][0] + sh[0][1] + sh[0][2] + sh[0][3];
    float R1 = sh[1][0] + sh[1][1] + sh[1][2] + sh[1][3];
    float R2 = sh[2][0] + sh[2][1] + sh[2][2] + sh[2][3];
    float R3 = sh[3][0] + sh[3][1] + sh[3][2] + sh[3][3];
    float S  = sh[4][0] + sh[4][1] + sh[4][2] + sh[4][3];
    rdot[0 * MD + m] = R0; rdot[1 * MD + m] = R1;
    rdot[2 * MD + m] = R2; rdot[3 * MD + m] = R3;
    nmn[m] = sqrtf(S);
  }
}

// ---------------- content softmax per read head ----------------
__global__ void content_kernel(const float* __restrict__ rdot, const float* __restrict__ nmn,
                               const float* __restrict__ rkn, const float* __restrict__ rs,
                               float* __restrict__ cont) {
  int r = blockIdx.x;
  int t = threadIdx.x;
  __shared__ float vals[MD];
  __shared__ float red[256];
  float strength = rs[r], kn = rkn[r];
  float mx = -3.4e38f;
  for (int m = t; m < MD; m += 256) {
    float v = rdot[r * MD + m] / (kn * nmn[m]) * strength;
    vals[m] = v; mx = fmaxf(mx, v);
  }
  red[t] = mx; __syncthreads();
  for (int s = 128; s; s >>= 1) { if (t < s) red[t] = fmaxf(red[t], red[t + s]); __syncthreads(); }
  mx = red[0]; __syncthreads();
  float sm = 0.f;
  for (int m = t; m < MD; m += 256) { float e = expf(vals[m] - mx); vals[m] = e; sm += e; }
  red[t] = sm; __syncthreads();
  for (int s = 128; s; s >>= 1) { if (t < s) red[t] += red[t + s]; __syncthreads(); }
  float inv = 1.f / red[0];
  for (int m = t; m < MD; m += 256) cont[r * MD + m] = vals[m] * inv;
}

// ---------------- link update + fused fwd row-sums ----------------
__global__ void link_kernel(const float* __restrict__ plink, const float* __restrict__ ww,
                            const float* __restrict__ pprec, const float* __restrict__ prw,
                            float* __restrict__ link_out, float* __restrict__ fwd) {
  int i = blockIdx.x;
  int w = blockIdx.y;
  int t = threadIdx.x;
  float wwi = ww[w * MD + i];
  const float4* pl = (const float4*)(plink + ((size_t)w * MD + i) * MD);
  const float4* wj = (const float4*)(ww + w * MD);
  const float4* pj = (const float4*)(pprec + w * MD);
  const float4* p0 = (const float4*)prw;
  const float4* p1 = (const float4*)(prw + MD);
  const float4* p2 = (const float4*)(prw + 2 * MD);
  const float4* p3 = (const float4*)(prw + 3 * MD);
  float4* lo = (float4*)(link_out + ((size_t)w * MD + i) * MD);
  float f0 = 0, f1 = 0, f2 = 0, f3 = 0;
  for (int c = t; c < MD / 4; c += 256) {
    float4 L = pl[c], WJ = wj[c], PJ = pj[c];
    float4 o;
    o.x = (1.f - wwi - WJ.x) * L.x + wwi * PJ.x;
    o.y = (1.f - wwi - WJ.y) * L.y + wwi * PJ.y;
    o.z = (1.f - wwi - WJ.z) * L.z + wwi * PJ.z;
    o.w = (1.f - wwi - WJ.w) * L.w + wwi * PJ.w;
    int j0 = c * 4;
    if ((unsigned)(i - j0) < 4u) ((float*)&o)[i - j0] = 0.f;
    lo[c] = o;
    float4 a = p0[c]; f0 += o.x * a.x + o.y * a.y + o.z * a.z + o.w * a.w;
    float4 b = p1[c]; f1 += o.x * b.x + o.y * b.y + o.z * b.z + o.w * b.w;
    float4 cc = p2[c]; f2 += o.x * cc.x + o.y * cc.y + o.z * cc.z + o.w * cc.w;
    float4 d = p3[c]; f3 += o.x * d.x + o.y * d.y + o.z * d.z + o.w * d.w;
  }
  f0 = waveReduceSum(f0); f1 = waveReduceSum(f1);
  f2 = waveReduceSum(f2); f3 = waveReduceSum(f3);
  __shared__ float sh[4][4];
  int wave = t >> 6, lane = t & 63;
  if (lane == 0) { sh[0][wave] = f0; sh[1][wave] = f1; sh[2][wave] = f2; sh[3][wave] = f3; }
  __syncthreads();
  if (t == 0) {
    fwd[(0 * NWD + w) * MD + i] = sh[0][0] + sh[0][1] + sh[0][2] + sh[0][3];
    fwd[(1 * NWD + w) * MD + i] = sh[1][0] + sh[1][1] + sh[1][2] + sh[1][3];
    fwd[(2 * NWD + w) * MD + i] = sh[2][0] + sh[2][1] + sh[2][2] + sh[2][3];
    fwd[(3 * NWD + w) * MD + i] = sh[3][0] + sh[3][1] + sh[3][2] + sh[3][3];
  }
}

// ---------------- bwd column sums over link ----------------
__global__ void bwd_kernel(const float* __restrict__ link, const float* __restrict__ prw,
                           float* __restrict__ bwd) {
  int mc = blockIdx.x, jt = blockIdx.y, w = blockIdx.z;
  int j = jt * 256 + threadIdx.x;
  const float* base = link + (size_t)w * MD * MD;
  float a0 = 0, a1 = 0, a2 = 0, a3 = 0;
  int m0 = mc * 256;
  for (int m = m0; m < m0 + 256; ++m) {
    float lv = base[(size_t)m * MD + j];
    a0 += prw[m] * lv;
    a1 += prw[MD + m] * lv;
    a2 += prw[2 * MD + m] * lv;
    a3 += prw[3 * MD + m] * lv;
  }
  atomicAdd(&bwd[(0 * NWD + w) * MD + j], a0);
  atomicAdd(&bwd[(1 * NWD + w) * MD + j], a1);
  atomicAdd(&bwd[(2 * NWD + w) * MD + j], a2);
  atomicAdd(&bwd[(3 * NWD + w) * MD + j], a3);
}

// ---------------- final read weights ----------------
__global__ void rw_kernel(const float* __restrict__ fwd, const float* __restrict__ bwd,
                          const float* __restrict__ cont, const float* __restrict__ rm,
                          float* __restrict__ out_rw) {
  int idx = blockIdx.x * 256 + threadIdx.x;  // r*MD + m
  int r = idx >> 12;
  int m = idx & (MD - 1);
  float v = rm[r * MODESD + 4] * cont[idx];
#pragma unroll
  for (int w = 0; w < NWD; ++w) {
    v += rm[r * MODESD + w] * bwd[(r * NWD + w) * MD + m];
    v += rm[r * MODESD + NWD + w] * fwd[(r * NWD + w) * MD + m];
  }
  out_rw[idx] = v;
}

// ---------------- read words ----------------
__global__ void rwords_kernel(const float* __restrict__ rw, const float* __restrict__ nm,
                              float* __restrict__ out_words) {
  int mc = blockIdx.x;
  int d = blockIdx.y * 256 + threadIdx.x;
  float a0 = 0, a1 = 0, a2 = 0, a3 = 0;
  int m0 = mc * 256;
  for (int m = m0; m < m0 + 256; ++m) {
    float v = nm[(size_t)m * WD + d];
    a0 += rw[m] * v;
    a1 += rw[MD + m] * v;
    a2 += rw[2 * MD + m] * v;
    a3 += rw[3 * MD + m] * v;
  }
  atomicAdd(&out_words[d], a0);
  atomicAdd(&out_words[WD + d], a1);
  atomicAdd(&out_words[2 * WD + d], a2);
  atomicAdd(&out_words[3 * WD + d], a3);
}

extern "C" void kernel_launch(void* const* d_in, const int* in_sizes, int n_in,
                              void* d_out, int out_size, void* d_ws, size_t ws_size,
                              hipStream_t stream) {
  (void)in_sizes; (void)n_in; (void)out_size; (void)ws_size;
  const float* x      = (const float*)d_in[0];
  const float* memory = (const float*)d_in[1];
  const float* prw    = (const float*)d_in[2];
  const float* pww    = (const float*)d_in[3];
  const float* plink  = (const float*)d_in[4];
  const float* pprec  = (const float*)d_in[5];
  const float* pusage = (const float*)d_in[6];
  float* ws  = (float*)d_ws;
  float* out = (float*)d_out;

  // zero accumulators early (stream order guarantees completion before use)
  hipMemsetAsync(ws + WS_BWD, 0, 32768 * sizeof(float), stream);
  hipMemsetAsync(out + O_WORDS, 0, 16384 * sizeof(float), stream);

  // GEMVs
  gemv_kernel<<<2048, 256, 0, stream>>>((const float*)d_in[7],  (const float*)d_in[8],  x, ws + WS_WV,   8192, 0);
  gemv_kernel<<<2048, 256, 0, stream>>>((const float*)d_in[9],  (const float*)d_in[10], x, ws + WS_EV,   8192, 1);
  gemv_kernel<<<1,    256, 0, stream>>>((const float*)d_in[11], (const float*)d_in[12], x, ws + WS_FG,      4, 1);
  gemv_kernel<<<1,    256, 0, stream>>>((const float*)d_in[13], (const float*)d_in[14], x, ws + WS_AG,      2, 1);
  gemv_kernel<<<1,    256, 0, stream>>>((const float*)d_in[15], (const float*)d_in[16], x, ws + WS_WG,      2, 1);
  gemv_kernel<<<5,    256, 0, stream>>>((const float*)d_in[17], (const float*)d_in[18], x, ws + WS_RM,     20, 1);
  gemv_kernel<<<2048, 256, 0, stream>>>((const float*)d_in[19], (const float*)d_in[20], x, ws + WS_WK,   8192, 1);
  gemv_kernel<<<1,    256, 0, stream>>>((const float*)d_in[21], (const float*)d_in[22], x, ws + WS_WSTR,    2, 0);
  gemv_kernel<<<4096, 256, 0, stream>>>((const float*)d_in[23], (const float*)d_in[24], x, ws + WS_RK,  16384, 0);
  gemv_kernel<<<1,    256, 0, stream>>>((const float*)d_in[25], (const float*)d_in[26], x, ws + WS_RS,      4, 0);

  norms_kernel<<<6, 256, 0, stream>>>(ws + WS_WK, ws + WS_RK, ws + WS_KN, ws + WS_RKN);
  usage_kernel<<<16, 256, 0, stream>>>(pusage, pww, prw, ws + WS_FG, ws + WS_UPRE);
  sim_kernel<<<4096, 256, 0, stream>>>(memory, ws + WS_WK, ws + WS_KN, ws + WS_SIM);
  ww_kernel<<<1, 1024, 0, stream>>>(ws + WS_SIM, ws + WS_UPRE, ws + WS_WSTR, ws + WS_AG,
                                    ws + WS_WG, pprec, out + O_WW, out + O_PREC, out + O_USAGE);
  newmem_kernel<<<4096, 256, 0, stream>>>(memory, out + O_WW, ws + WS_EV, ws + WS_WV,
                                          ws + WS_RK, out + O_NM, ws + WS_RDOT, ws + WS_NMN);
  content_kernel<<<4, 256, 0, stream>>>(ws + WS_RDOT, ws + WS_NMN, ws + WS_RKN, ws + WS_RS, ws + WS_CONT);
  link_kernel<<<dim3(MD, NWD), 256, 0, stream>>>(plink, out + O_WW, pprec, prw,
                                                 out + O_LINK, ws + WS_FWD);
  bwd_kernel<<<dim3(16, 16, 2), 256, 0, stream>>>(out + O_LINK, prw, ws + WS_BWD);
  rw_kernel<<<64, 256, 0, stream>>>(ws + WS_FWD, ws + WS_BWD, ws + WS_CONT, ws + WS_RM, out + O_RW);
  rwords_kernel<<<dim3(16, 16), 256, 0, stream>>>(out + O_RW, out + O_NM, out + O_WORDS);
}

// Round 2
// 690.608 us; speedup vs baseline: 1.1876x; 1.1876x over previous
//
#include <hip/hip_runtime.h>
#include <math.h>

#define HD 1024
#define MD 4096
#define WD 4096
#define RD 4
#define NWD 2
#define MODESD 5
#define EPSF 0.001f

// ---- d_out offsets (floats), in reference return order ----
#define O_WORDS 0            // read_words   R*WD        = 16384
#define O_NM    16384        // new_memory   MD*WD       = 16777216
#define O_RW    16793600     // read_weights R*MD        = 16384
#define O_WW    16809984     // write_weights NW*MD      = 8192
#define O_LINK  16818176     // link         NW*MD*MD    = 33554432
#define O_PREC  50372608     // precedence   NW*MD       = 8192
#define O_USAGE 50380800     // usage        MD          = 4096

// ---- workspace offsets (floats) ----
#define WS_WV   0            // 8192
#define WS_EV   8192         // 8192 (sigmoid)
#define WS_WK   16384        // 8192 (sigmoid)
#define WS_RK   24576        // 16384
#define WS_FG   40960        // 4  (sigmoid)
#define WS_AG   40976        // 2  (sigmoid)
#define WS_WG   40992        // 2  (sigmoid)
#define WS_RM   41008        // 20 (sigmoid)
#define WS_WSTR 41040        // 2
#define WS_RS   41056        // 4
#define WS_KN   41072        // 2
#define WS_RKN  41088        // 4
#define WS_UPRE 41104        // 4096   (usage pre-allocation; aliased as u1 by update0)
#define WS_SIM  45200        // NW*MD = 8192
#define WS_RDOT 53392        // R*MD  = 16384
#define WS_NMN  69776        // 4096
#define WS_CONT 73872        // R*MD  = 16384
#define WS_FWD  90256        // R*NW*MD = 32768
#define WS_CW   123024       // NW*MD = 8192 (write content softmax)
#define WS_UU   131216       // 4096 (u = EPS+(1-EPS)*usage, reused head0->head1)
#define WS_LU   135312       // 4096 (log u, reused)
// ---- zeroed region (single memset) ----
#define WS_S0   139408       // 4096 rank-product log-sum, head 0
#define WS_S1   143504       // 4096 rank-product log-sum, head 1
#define WS_WWSUM 147600      // 4 (2 used)
#define WS_BWD  147604       // R*NW*MD = 32768
#define WS_ZERO_START WS_S0
#define WS_ZERO_COUNT (4096 + 4096 + 4 + 32768)

__device__ __forceinline__ float waveReduceSum(float v) {
#pragma unroll
  for (int o = 32; o; o >>= 1) v += __shfl_down(v, o, 64);
  return v;
}

// ---------------- GEMV: out[row] = act(x . W[row,:] + b[row]) ----------------
__global__ void gemv_kernel(const float* __restrict__ W, const float* __restrict__ b,
                            const float* __restrict__ x, float* __restrict__ out,
                            int rows, int act) {
  __shared__ float4 xs[HD / 4];
  int t = threadIdx.x;
  const float4* x4 = (const float4*)x;
  xs[t] = x4[t];
  __syncthreads();
  int wave = t >> 6, lane = t & 63;
  int row = blockIdx.x * 4 + wave;
  if (row >= rows) return;
  const float4* W4 = (const float4*)(W + (size_t)row * HD);
  float acc = 0.f;
#pragma unroll
  for (int i = 0; i < 4; ++i) {
    float4 w = W4[i * 64 + lane];
    float4 xv = xs[i * 64 + lane];
    acc += w.x * xv.x + w.y * xv.y + w.z * xv.z + w.w * xv.w;
  }
  acc = waveReduceSum(acc);
  if (lane == 0) {
    float v = acc + b[row];
    if (act) v = 1.f / (1.f + expf(-v));
    out[row] = v;
  }
}

// ---------------- fused tiny GEMVs (34 rows total) ----------------
// blocks 0..33, one row each; mapping table below.
__global__ void small_gemv_kernel(const float* __restrict__ x,
                                  const float* __restrict__ Wfg, const float* __restrict__ bfg,
                                  const float* __restrict__ Wag, const float* __restrict__ bag,
                                  const float* __restrict__ Wwg, const float* __restrict__ bwg,
                                  const float* __restrict__ Wrm, const float* __restrict__ brm,
                                  const float* __restrict__ Wws, const float* __restrict__ bws,
                                  const float* __restrict__ Wrs, const float* __restrict__ brs,
                                  float* __restrict__ ws) {
  int blk = blockIdx.x;
  const float* W; const float* b; float* out; int row; int act;
  if (blk < 4)       { W = Wfg; b = bfg; out = ws + WS_FG;   row = blk;       act = 1; }
  else if (blk < 6)  { W = Wag; b = bag; out = ws + WS_AG;   row = blk - 4;   act = 1; }
  else if (blk < 8)  { W = Wwg; b = bwg; out = ws + WS_WG;   row = blk - 6;   act = 1; }
  else if (blk < 28) { W = Wrm; b = brm; out = ws + WS_RM;   row = blk - 8;   act = 1; }
  else if (blk < 30) { W = Wws; b = bws; out = ws + WS_WSTR; row = blk - 28;  act = 0; }
  else               { W = Wrs; b = brs; out = ws + WS_RS;   row = blk - 30;  act = 0; }
  int t = threadIdx.x;
  const float4* W4 = (const float4*)(W + (size_t)row * HD);
  const float4* x4 = (const float4*)x;
  float4 w = W4[t], xv = x4[t];
  float acc = w.x * xv.x + w.y * xv.y + w.z * xv.z + w.w * xv.w;
  acc = waveReduceSum(acc);
  __shared__ float sh[4];
  int wave = t >> 6, lane = t & 63;
  if (lane == 0) sh[wave] = acc;
  __syncthreads();
  if (t == 0) {
    float v = sh[0] + sh[1] + sh[2] + sh[3] + b[row];
    if (act) v = 1.f / (1.f + expf(-v));
    out[row] = v;
  }
}

// ---------------- key norms ----------------
__global__ void norms_kernel(const float* __restrict__ wk, const float* __restrict__ rk,
                             float* __restrict__ kn, float* __restrict__ rkn) {
  int v = blockIdx.x;  // 0..5
  const float* p = (v < 2) ? (wk + v * WD) : (rk + (v - 2) * WD);
  float s = 0.f;
  for (int d = threadIdx.x; d < WD; d += 256) { float t = p[d]; s += t * t; }
  s = waveReduceSum(s);
  __shared__ float sh[4];
  int wave = threadIdx.x >> 6, lane = threadIdx.x & 63;
  if (lane == 0) sh[wave] = s;
  __syncthreads();
  if (threadIdx.x == 0) {
    float r = sqrtf(sh[0] + sh[1] + sh[2] + sh[3]);
    if (v < 2) kn[v] = r; else rkn[v - 2] = r;
  }
}

// ---------------- usage pre-allocation + uu/logu prep (head 0) ----------------
__global__ void usage_kernel(const float* __restrict__ pusage, const float* __restrict__ pww,
                             const float* __restrict__ prw, const float* __restrict__ fg,
                             float* __restrict__ upre, float* __restrict__ uu,
                             float* __restrict__ lu) {
  int m = blockIdx.x * 256 + threadIdx.x;
  float pw = 1.f;
#pragma unroll
  for (int w = 0; w < NWD; ++w) pw *= pww[w * MD + m];
  float pu = pusage[m];
  float u = pu + (1.f - pu) * (1.f - pw);
  float pr = 1.f;
#pragma unroll
  for (int r = 0; r < RD; ++r) pr *= fg[r] * prw[r * MD + m];
  float up = u * (1.f - pr);
  upre[m] = up;
  float v = EPSF + (1.f - EPSF) * up;
  uu[m] = v;
  lu[m] = logf(v);
}

// ---------------- write-key similarity over memory ----------------
__global__ void sim_kernel(const float* __restrict__ mem, const float* __restrict__ wk,
                           const float* __restrict__ kn, float* __restrict__ sim) {
  int m = blockIdx.x;
  int t = threadIdx.x;
  const float4* row = (const float4*)(mem + (size_t)m * WD);
  const float4* k0 = (const float4*)wk;
  const float4* k1 = (const float4*)(wk + WD);
  float d0 = 0, d1 = 0, s = 0;
  for (int i = t; i < WD / 4; i += 256) {
    float4 v = row[i], a = k0[i], b = k1[i];
    d0 += v.x * a.x + v.y * a.y + v.z * a.z + v.w * a.w;
    d1 += v.x * b.x + v.y * b.y + v.z * b.z + v.w * b.w;
    s  += v.x * v.x + v.y * v.y + v.z * v.z + v.w * v.w;
  }
  d0 = waveReduceSum(d0); d1 = waveReduceSum(d1); s = waveReduceSum(s);
  __shared__ float sh[3][4];
  int wave = t >> 6, lane = t & 63;
  if (lane == 0) { sh[0][wave] = d0; sh[1][wave] = d1; sh[2][wave] = s; }
  __syncthreads();
  if (t == 0) {
    float D0 = sh[0][0] + sh[0][1] + sh[0][2] + sh[0][3];
    float D1 = sh[1][0] + sh[1][1] + sh[1][2] + sh[1][3];
    float S  = sh[2][0] + sh[2][1] + sh[2][2] + sh[2][3];
    float mn = sqrtf(S);
    sim[0 * MD + m] = D0 / (kn[0] * mn + EPSF);
    sim[1 * MD + m] = D1 / (kn[1] * mn + EPSF);
  }
}

// ---------------- write content softmax (per head) ----------------
__global__ void cw_kernel(const float* __restrict__ sim, const float* __restrict__ wstr,
                          float* __restrict__ cw) {
  int h = blockIdx.x;
  int t = threadIdx.x;
  __shared__ float vals[MD];
  __shared__ float red[256];
  float beta = 1.f + log1pf(expf(wstr[h]));
  float mx = -3.4e38f;
  for (int m = t; m < MD; m += 256) {
    float v = sim[h * MD + m] * beta;
    vals[m] = v; mx = fmaxf(mx, v);
  }
  red[t] = mx; __syncthreads();
  for (int s = 128; s; s >>= 1) { if (t < s) red[t] = fmaxf(red[t], red[t + s]); __syncthreads(); }
  mx = red[0]; __syncthreads();
  float sm = 0.f;
  for (int m = t; m < MD; m += 256) { float e = expf(vals[m] - mx); vals[m] = e; sm += e; }
  red[t] = sm; __syncthreads();
  for (int s = 128; s; s >>= 1) { if (t < s) red[t] += red[t + s]; __syncthreads(); }
  float inv = 1.f / red[0];
  for (int m = t; m < MD; m += 256) cw[h * MD + m] = vals[m] * inv;
}

// ---------------- rank-product partial sums ----------------
// a[i] = (1-u[i]) * exp( sum_j log u[j] * [ u[j]<u[i] || (u[j]==u[i] && j<i) ] )
// grid (16,16): block (bi,bj) accumulates the bj-th j-chunk into S[i] for the bi-th i-chunk.
__global__ void alloc_partial_kernel(const float* __restrict__ uu, const float* __restrict__ lu,
                                     float* __restrict__ S) {
  __shared__ float4 us[64], ls[64];
  int t = threadIdx.x;
  int j0 = blockIdx.y * 256;
  if (t < 64) {
    us[t] = ((const float4*)(uu + j0))[t];
    ls[t] = ((const float4*)(lu + j0))[t];
  }
  __syncthreads();
  int i = blockIdx.x * 256 + t;
  float ui = uu[i];
  float s = 0.f;
#pragma unroll 4
  for (int c = 0; c < 64; ++c) {
    float4 u4 = us[c], l4 = ls[c];
    int jb = j0 + c * 4;
    s += ((u4.x < ui) || (u4.x == ui && (jb + 0) < i)) ? l4.x : 0.f;
    s += ((u4.y < ui) || (u4.y == ui && (jb + 1) < i)) ? l4.y : 0.f;
    s += ((u4.z < ui) || (u4.z == ui && (jb + 2) < i)) ? l4.z : 0.f;
    s += ((u4.w < ui) || (u4.w == ui && (jb + 3) < i)) ? l4.w : 0.f;
  }
  atomicAdd(&S[i], s);
}

// ---------------- head-0 update: a0, ww0, usage1, uu/logu for head 1 ----------------
__global__ void update0_kernel(const float* __restrict__ S0, const float* __restrict__ cw,
                               const float* __restrict__ ag, const float* __restrict__ wg,
                               const float* __restrict__ upre, float* __restrict__ uu,
                               float* __restrict__ lu, float* __restrict__ u1,
                               float* __restrict__ out_ww, float* __restrict__ wwsum) {
  int m = blockIdx.x * 256 + threadIdx.x;
  float agv = ag[0], wgv = wg[0];
  float uum = uu[m];
  float a = (1.f - uum) * expf(S0[m]);
  float w = wgv * (agv * a + (1.f - agv) * cw[m]);
  out_ww[m] = w;
  float up = upre[m];
  float un = up + (1.f - up) * (agv * wgv) * a;
  u1[m] = un;                      // aliases upre — same-index rmw, safe
  float v = EPSF + (1.f - EPSF) * un;
  uu[m] = v;                       // overwrite for head 1
  lu[m] = logf(v);
  float p = waveReduceSum(w);
  if ((threadIdx.x & 63) == 0) atomicAdd(&wwsum[0], p);
}

// ---------------- head-1 update: a1, ww1, final usage ----------------
__global__ void update1_kernel(const float* __restrict__ S1, const float* __restrict__ cw,
                               const float* __restrict__ ag, const float* __restrict__ wg,
                               const float* __restrict__ u1, const float* __restrict__ uu,
                               float* __restrict__ out_ww, float* __restrict__ out_usage,
                               float* __restrict__ wwsum) {
  int m = blockIdx.x * 256 + threadIdx.x;
  float agv = ag[1], wgv = wg[1];
  float uum = uu[m];
  float a = (1.f - uum) * expf(S1[m]);
  float w = wgv * (agv * a + (1.f - agv) * cw[MD + m]);
  out_ww[MD + m] = w;
  float un = u1[m];
  out_usage[m] = un + (1.f - un) * (agv * wgv) * a;
  float p = waveReduceSum(w);
  if ((threadIdx.x & 63) == 0) atomicAdd(&wwsum[1], p);
}

// ---------------- precedence ----------------
__global__ void prec_kernel(const float* __restrict__ ww, const float* __restrict__ wwsum,
                            const float* __restrict__ pprec, float* __restrict__ out_prec) {
  int m = blockIdx.x * 256 + threadIdx.x;
  float s0 = wwsum[0], s1 = wwsum[1];
  out_prec[m] = (1.f - s0) * pprec[m] + ww[m];
  out_prec[MD + m] = (1.f - s1) * pprec[MD + m] + ww[MD + m];
}

// ---------------- new_memory + fused rdot + new norms ----------------
__global__ void newmem_kernel(const float* __restrict__ mem, const float* __restrict__ ww,
                              const float* __restrict__ ev, const float* __restrict__ wvv,
                              const float* __restrict__ rk, float* __restrict__ nm_out,
                              float* __restrict__ rdot, float* __restrict__ nmn) {
  int m = blockIdx.x;
  int t = threadIdx.x;
  float w0 = ww[m], w1 = ww[MD + m];
  const float4* row = (const float4*)(mem + (size_t)m * WD);
  const float4* e0 = (const float4*)ev;
  const float4* e1 = (const float4*)(ev + WD);
  const float4* v0 = (const float4*)wvv;
  const float4* v1 = (const float4*)(wvv + WD);
  const float4* k0 = (const float4*)rk;
  const float4* k1 = (const float4*)(rk + WD);
  const float4* k2 = (const float4*)(rk + 2 * WD);
  const float4* k3 = (const float4*)(rk + 3 * WD);
  float4* outp = (float4*)(nm_out + (size_t)m * WD);
  float r0 = 0, r1 = 0, r2 = 0, r3 = 0, s2 = 0;
  for (int i = t; i < WD / 4; i += 256) {
    float4 mv = row[i], ea = e0[i], eb = e1[i], va = v0[i], vb = v1[i];
    float4 o;
    o.x = mv.x * (1.f - w0 * ea.x) * (1.f - w1 * eb.x) + w0 * va.x + w1 * vb.x;
    o.y = mv.y * (1.f - w0 * ea.y) * (1.f - w1 * eb.y) + w0 * va.y + w1 * vb.y;
    o.z = mv.z * (1.f - w0 * ea.z) * (1.f - w1 * eb.z) + w0 * va.z + w1 * vb.z;
    o.w = mv.w * (1.f - w0 * ea.w) * (1.f - w1 * eb.w) + w0 * va.w + w1 * vb.w;
    outp[i] = o;
    float4 a = k0[i]; r0 += o.x * a.x + o.y * a.y + o.z * a.z + o.w * a.w;
    float4 b = k1[i]; r1 += o.x * b.x + o.y * b.y + o.z * b.z + o.w * b.w;
    float4 c = k2[i]; r2 += o.x * c.x + o.y * c.y + o.z * c.z + o.w * c.w;
    float4 d = k3[i]; r3 += o.x * d.x + o.y * d.y + o.z * d.z + o.w * d.w;
    s2 += o.x * o.x + o.y * o.y + o.z * o.z + o.w * o.w;
  }
  r0 = waveReduceSum(r0); r1 = waveReduceSum(r1); r2 = waveReduceSum(r2);
  r3 = waveReduceSum(r3); s2 = waveReduceSum(s2);
  __shared__ float sh[5][4];
  int wave = t >> 6, lane = t & 63;
  if (lane == 0) { sh[0][wave] = r0; sh[1][wave] = r1; sh[2][wave] = r2; sh[3][wave] = r3; sh[4][wave] = s2; }
  __syncthreads();
  if (t == 0) {
    rdot[0 * MD + m] = sh[0][0] + sh[0][1] + sh[0][2] + sh[0][3];
    rdot[1 * MD + m] = sh[1][0] + sh[1][1] + sh[1][2] + sh[1][3];
    rdot[2 * MD + m] = sh[2][0] + sh[2][1] + sh[2][2] + sh[2][3];
    rdot[3 * MD + m] = sh[3][0] + sh[3][1] + sh[3][2] + sh[3][3];
    nmn[m] = sqrtf(sh[4][0] + sh[4][1] + sh[4][2] + sh[4][3]);
  }
}

// ---------------- content softmax per read head ----------------
__global__ void content_kernel(const float* __restrict__ rdot, const float* __restrict__ nmn,
                               const float* __restrict__ rkn, const float* __restrict__ rs,
                               float* __restrict__ cont) {
  int r = blockIdx.x;
  int t = threadIdx.x;
  __shared__ float vals[MD];
  __shared__ float red[256];
  float strength = rs[r], kn = rkn[r];
  float mx = -3.4e38f;
  for (int m = t; m < MD; m += 256) {
    float v = rdot[r * MD + m] / (kn * nmn[m]) * strength;
    vals[m] = v; mx = fmaxf(mx, v);
  }
  red[t] = mx; __syncthreads();
  for (int s = 128; s; s >>= 1) { if (t < s) red[t] = fmaxf(red[t], red[t + s]); __syncthreads(); }
  mx = red[0]; __syncthreads();
  float sm = 0.f;
  for (int m = t; m < MD; m += 256) { float e = expf(vals[m] - mx); vals[m] = e; sm += e; }
  red[t] = sm; __syncthreads();
  for (int s = 128; s; s >>= 1) { if (t < s) red[t] += red[t + s]; __syncthreads(); }
  float inv = 1.f / red[0];
  for (int m = t; m < MD; m += 256) cont[r * MD + m] = vals[m] * inv;
}

// ---------------- link update + fused fwd row-sums ----------------
__global__ void link_kernel(const float* __restrict__ plink, const float* __restrict__ ww,
                            const float* __restrict__ pprec, const float* __restrict__ prw,
                            float* __restrict__ link_out, float* __restrict__ fwd) {
  int i = blockIdx.x;
  int w = blockIdx.y;
  int t = threadIdx.x;
  float wwi = ww[w * MD + i];
  const float4* pl = (const float4*)(plink + ((size_t)w * MD + i) * MD);
  const float4* wj = (const float4*)(ww + w * MD);
  const float4* pj = (const float4*)(pprec + w * MD);
  const float4* p0 = (const float4*)prw;
  const float4* p1 = (const float4*)(prw + MD);
  const float4* p2 = (const float4*)(prw + 2 * MD);
  const float4* p3 = (const float4*)(prw + 3 * MD);
  float4* lo = (float4*)(link_out + ((size_t)w * MD + i) * MD);
  float f0 = 0, f1 = 0, f2 = 0, f3 = 0;
  for (int c = t; c < MD / 4; c += 256) {
    float4 L = pl[c], WJ = wj[c], PJ = pj[c];
    float4 o;
    o.x = (1.f - wwi - WJ.x) * L.x + wwi * PJ.x;
    o.y = (1.f - wwi - WJ.y) * L.y + wwi * PJ.y;
    o.z = (1.f - wwi - WJ.z) * L.z + wwi * PJ.z;
    o.w = (1.f - wwi - WJ.w) * L.w + wwi * PJ.w;
    int j0 = c * 4;
    if ((unsigned)(i - j0) < 4u) ((float*)&o)[i - j0] = 0.f;
    lo[c] = o;
    float4 a = p0[c]; f0 += o.x * a.x + o.y * a.y + o.z * a.z + o.w * a.w;
    float4 b = p1[c]; f1 += o.x * b.x + o.y * b.y + o.z * b.z + o.w * b.w;
    float4 cc = p2[c]; f2 += o.x * cc.x + o.y * cc.y + o.z * cc.z + o.w * cc.w;
    float4 d = p3[c]; f3 += o.x * d.x + o.y * d.y + o.z * d.z + o.w * d.w;
  }
  f0 = waveReduceSum(f0); f1 = waveReduceSum(f1);
  f2 = waveReduceSum(f2); f3 = waveReduceSum(f3);
  __shared__ float sh[4][4];
  int wave = t >> 6, lane = t & 63;
  if (lane == 0) { sh[0][wave] = f0; sh[1][wave] = f1; sh[2][wave] = f2; sh[3][wave] = f3; }
  __syncthreads();
  if (t == 0) {
    fwd[(0 * NWD + w) * MD + i] = sh[0][0] + sh[0][1] + sh[0][2] + sh[0][3];
    fwd[(1 * NWD + w) * MD + i] = sh[1][0] + sh[1][1] + sh[1][2] + sh[1][3];
    fwd[(2 * NWD + w) * MD + i] = sh[2][0] + sh[2][1] + sh[2][2] + sh[2][3];
    fwd[(3 * NWD + w) * MD + i] = sh[3][0] + sh[3][1] + sh[3][2] + sh[3][3];
  }
}

// ---------------- bwd column sums over link ----------------
__global__ void bwd_kernel(const float* __restrict__ link, const float* __restrict__ prw,
                           float* __restrict__ bwd) {
  int mc = blockIdx.x, jt = blockIdx.y, w = blockIdx.z;
  int j = jt * 256 + threadIdx.x;
  const float* base = link + (size_t)w * MD * MD;
  float a0 = 0, a1 = 0, a2 = 0, a3 = 0;
  int m0 = mc * 256;
  for (int m = m0; m < m0 + 256; ++m) {
    float lv = base[(size_t)m * MD + j];
    a0 += prw[m] * lv;
    a1 += prw[MD + m] * lv;
    a2 += prw[2 * MD + m] * lv;
    a3 += prw[3 * MD + m] * lv;
  }
  atomicAdd(&bwd[(0 * NWD + w) * MD + j], a0);
  atomicAdd(&bwd[(1 * NWD + w) * MD + j], a1);
  atomicAdd(&bwd[(2 * NWD + w) * MD + j], a2);
  atomicAdd(&bwd[(3 * NWD + w) * MD + j], a3);
}

// ---------------- final read weights ----------------
__global__ void rw_kernel(const float* __restrict__ fwd, const float* __restrict__ bwd,
                          const float* __restrict__ cont, const float* __restrict__ rm,
                          float* __restrict__ out_rw) {
  int idx = blockIdx.x * 256 + threadIdx.x;  // r*MD + m
  int r = idx >> 12;
  int m = idx & (MD - 1);
  float v = rm[r * MODESD + 4] * cont[idx];
#pragma unroll
  for (int w = 0; w < NWD; ++w) {
    v += rm[r * MODESD + w] * bwd[(r * NWD + w) * MD + m];
    v += rm[r * MODESD + NWD + w] * fwd[(r * NWD + w) * MD + m];
  }
  out_rw[idx] = v;
}

// ---------------- read words ----------------
__global__ void rwords_kernel(const float* __restrict__ rw, const float* __restrict__ nm,
                              float* __restrict__ out_words) {
  int mc = blockIdx.x;
  int d = blockIdx.y * 256 + threadIdx.x;
  float a0 = 0, a1 = 0, a2 = 0, a3 = 0;
  int m0 = mc * 256;
  for (int m = m0; m < m0 + 256; ++m) {
    float v = nm[(size_t)m * WD + d];
    a0 += rw[m] * v;
    a1 += rw[MD + m] * v;
    a2 += rw[2 * MD + m] * v;
    a3 += rw[3 * MD + m] * v;
  }
  atomicAdd(&out_words[d], a0);
  atomicAdd(&out_words[WD + d], a1);
  atomicAdd(&out_words[2 * WD + d], a2);
  atomicAdd(&out_words[3 * WD + d], a3);
}

extern "C" void kernel_launch(void* const* d_in, const int* in_sizes, int n_in,
                              void* d_out, int out_size, void* d_ws, size_t ws_size,
                              hipStream_t stream) {
  (void)in_sizes; (void)n_in; (void)out_size; (void)ws_size;
  const float* x      = (const float*)d_in[0];
  const float* memory = (const float*)d_in[1];
  const float* prw    = (const float*)d_in[2];
  const float* pww    = (const float*)d_in[3];
  const float* plink  = (const float*)d_in[4];
  const float* pprec  = (const float*)d_in[5];
  const float* pusage = (const float*)d_in[6];
  float* ws  = (float*)d_ws;
  float* out = (float*)d_out;

  hipMemsetAsync(ws + WS_ZERO_START, 0, WS_ZERO_COUNT * sizeof(float), stream);
  hipMemsetAsync(out + O_WORDS, 0, 16384 * sizeof(float), stream);

  // big GEMVs
  gemv_kernel<<<2048, 256, 0, stream>>>((const float*)d_in[7],  (const float*)d_in[8],  x, ws + WS_WV, 8192, 0);
  gemv_kernel<<<2048, 256, 0, stream>>>((const float*)d_in[9],  (const float*)d_in[10], x, ws + WS_EV, 8192, 1);
  gemv_kernel<<<2048, 256, 0, stream>>>((const float*)d_in[19], (const float*)d_in[20], x, ws + WS_WK, 8192, 1);
  gemv_kernel<<<4096, 256, 0, stream>>>((const float*)d_in[23], (const float*)d_in[24], x, ws + WS_RK, 16384, 0);
  // fused tiny GEMVs
  small_gemv_kernel<<<34, 256, 0, stream>>>(x,
      (const float*)d_in[11], (const float*)d_in[12],   // fg
      (const float*)d_in[13], (const float*)d_in[14],   // ag
      (const float*)d_in[15], (const float*)d_in[16],   // wg
      (const float*)d_in[17], (const float*)d_in[18],   // rm
      (const float*)d_in[21], (const float*)d_in[22],   // wstr
      (const float*)d_in[25], (const float*)d_in[26],   // rs
      ws);

  norms_kernel<<<6, 256, 0, stream>>>(ws + WS_WK, ws + WS_RK, ws + WS_KN, ws + WS_RKN);
  usage_kernel<<<16, 256, 0, stream>>>(pusage, pww, prw, ws + WS_FG, ws + WS_UPRE, ws + WS_UU, ws + WS_LU);
  sim_kernel<<<4096, 256, 0, stream>>>(memory, ws + WS_WK, ws + WS_KN, ws + WS_SIM);
  cw_kernel<<<2, 256, 0, stream>>>(ws + WS_SIM, ws + WS_WSTR, ws + WS_CW);

  // head 0 allocation (rank-product) + update
  alloc_partial_kernel<<<dim3(16, 16), 256, 0, stream>>>(ws + WS_UU, ws + WS_LU, ws + WS_S0);
  update0_kernel<<<16, 256, 0, stream>>>(ws + WS_S0, ws + WS_CW, ws + WS_AG, ws + WS_WG,
                                         ws + WS_UPRE, ws + WS_UU, ws + WS_LU, ws + WS_UPRE,
                                         out + O_WW, ws + WS_WWSUM);
  // head 1
  alloc_partial_kernel<<<dim3(16, 16), 256, 0, stream>>>(ws + WS_UU, ws + WS_LU, ws + WS_S1);
  update1_kernel<<<16, 256, 0, stream>>>(ws + WS_S1, ws + WS_CW, ws + WS_AG, ws + WS_WG,
                                         ws + WS_UPRE, ws + WS_UU, out + O_WW, out + O_USAGE,
                                         ws + WS_WWSUM);
  prec_kernel<<<16, 256, 0, stream>>>(out + O_WW, ws + WS_WWSUM, pprec, out + O_PREC);

  newmem_kernel<<<4096, 256, 0, stream>>>(memory, out + O_WW, ws + WS_EV, ws + WS_WV,
                                          ws + WS_RK, out + O_NM, ws + WS_RDOT, ws + WS_NMN);
  content_kernel<<<4, 256, 0, stream>>>(ws + WS_RDOT, ws + WS_NMN, ws + WS_RKN, ws + WS_RS, ws + WS_CONT);
  link_kernel<<<dim3(MD, NWD), 256, 0, stream>>>(plink, out + O_WW, pprec, prw,
                                                 out + O_LINK, ws + WS_FWD);
  bwd_kernel<<<dim3(16, 16, 2), 256, 0, stream>>>(out + O_LINK, prw, ws + WS_BWD);
  rw_kernel<<<64, 256, 0, stream>>>(ws + WS_FWD, ws + WS_BWD, ws + WS_CONT, ws + WS_RM, out + O_RW);
  rwords_kernel<<<dim3(16, 16), 256, 0, stream>>>(out + O_RW, out + O_NM, out + O_WORDS);
}